// Round 8
// baseline (231.319 us; speedup 1.0000x reference)
//
#include <hip/hip_runtime.h>
#include <math.h>

// DeepseekV3 TopK router, MI355X — R13 (resubmit; R7 bench was a GPU-broker
// acquisition timeout) = R11's persistent-prefetch structure with R12's
// de-spill fixes. Evidence chain: R11 (persistent, 64-VGPR cap) = 96us
// router, 70MB scratch; R12 (non-persistent, de-spilled, 202.4us total) =
// ~47.5us router — de-spilling alone bought little, so the router is
// LATENCY-bound: 8 block-rounds/CU each expose ~900cy of HBM latency +
// barrier/straggler tails. R13 removes the exposure: 512 persistent blocks
// (2/CU, matching the 4-waves/SIMD VGPR occupancy), 4 token-slices each,
// slice i+1's global loads issued mid-phase-A of slice i into freed x[]
// halves. waves_per_eu(4) -> 128-reg budget (peak live ~90, no spill).
// Rotating phase-B wave; two barriers per slice guard the shared kbuf.
// Bias in padded LDS [8][36]. Score arithmetic frozen (precise expf, NR
// recip, u64 keys, Batcher networks) -> bit-identical (absmax 0.001953125).

constexpr int N_EXPERTS  = 256;
constexpr int N_GROUP    = 8;
constexpr int EG         = 32;
constexpr int TOPK_GROUP = 4;
constexpr int TOP_K      = 8;
constexpr int BLOCK      = 512;              // 64 tokens per slice
constexpr int TPB_TOK    = BLOCK / N_GROUP;  // 64

typedef unsigned int u32;
typedef unsigned long long u64;

// monotone map: a<b (float) <=> M(a)<M(b) (u32)
__device__ __forceinline__ u32 fmono(float f) {
  const u32 u = __float_as_uint(f);
  return u ^ ((u32)((int)u >> 31) | 0x80000000u);
}
__device__ __forceinline__ float fmono_inv(u32 m) {
  const u32 u = (m & 0x80000000u) ? (m ^ 0x80000000u) : ~m;
  return __uint_as_float(u);
}
// key: larger = (bigger value, then smaller index)
__device__ __forceinline__ u64 mkkey(float v, int idx) {
  return ((u64)fmono(v) << 32) | (u32)(255 - idx);
}
__device__ __forceinline__ int key_idx(u64 k) { return 255 - (int)(k & 0xFFu); }
__device__ __forceinline__ float key_val(u64 k) { return fmono_inv((u32)(k >> 32)); }

// reciprocal of d in (1,2): v_rcp_f32 + 2 NR refinements. VCC-free, <=1 ulp.
__device__ __forceinline__ float recip_nr(float d) {
  float r = __builtin_amdgcn_rcpf(d);
  r = __builtin_fmaf(__builtin_fmaf(-d, r, 1.0f), r, r);
  r = __builtin_fmaf(__builtin_fmaf(-d, r, 1.0f), r, r);
  return r;
}

// descending compare-swap: larger key to a
__device__ __forceinline__ void kswap(u64& a, u64& b) {
  const bool sw = b > a;
  const u64 t = sw ? b : a;
  b = sw ? a : b;
  a = t;
}

// Batcher odd-even mergesort network for 8 (19 comparators), descending.
__device__ __forceinline__ void sort8(u64 (&k)[8]) {
  kswap(k[0], k[1]); kswap(k[2], k[3]); kswap(k[4], k[5]); kswap(k[6], k[7]);
  kswap(k[0], k[2]); kswap(k[1], k[3]); kswap(k[4], k[6]); kswap(k[5], k[7]);
  kswap(k[1], k[2]); kswap(k[5], k[6]);
  kswap(k[0], k[4]); kswap(k[1], k[5]); kswap(k[2], k[6]); kswap(k[3], k[7]);
  kswap(k[2], k[4]); kswap(k[3], k[5]);
  kswap(k[1], k[2]); kswap(k[3], k[4]); kswap(k[5], k[6]);
}

// A = top-8 of (A, B); both descending sorted. Keys are unique -> exact.
__device__ __forceinline__ void merge8(u64 (&A)[8], const u64 (&B)[8]) {
  u64 R[8];
#pragma unroll
  for (int i = 0; i < 8; ++i) {
    const bool a = A[i] >= B[7 - i];
    R[i] = a ? A[i] : B[7 - i];
  }
  kswap(R[0], R[4]); kswap(R[1], R[5]); kswap(R[2], R[6]); kswap(R[3], R[7]);
  kswap(R[0], R[2]); kswap(R[1], R[3]); kswap(R[4], R[6]); kswap(R[5], R[7]);
  kswap(R[0], R[1]); kswap(R[2], R[3]); kswap(R[4], R[5]); kswap(R[6], R[7]);
#pragma unroll
  for (int i = 0; i < 8; ++i) A[i] = R[i];
}

// phase-B list read: 4x ds_read_b128, conflict-free via the 2-level swizzle.
__device__ __forceinline__ void load_list(const ulonglong2 (*kb)[4], int j,
                                          int s, u64 (&L)[8]) {
  const int rr = (8 * j + s) ^ ((j >> 2) & 1);  // (r>>5)&1 == (j>>2)&1, s<8
  const int sw = j & 3;                         // (r>>3)&3 == j&3
#pragma unroll
  for (int p = 0; p < 4; ++p) {
    const ulonglong2 v = kb[rr][p ^ sw];
    L[2 * p]     = v.x;
    L[2 * p + 1] = v.y;
  }
}

// one 8-element chunk: sigmoid+bias -> keys -> sort8 -> merge into K
__device__ __forceinline__ void chunk_sort(u64 (&K)[8], const float4 xa,
                                           const float4 xb, const float4 ba,
                                           const float4 bv, const int idx0,
                                           const bool first) {
  u64 C[8];
  const float xs[8] = {xa.x, xa.y, xa.z, xa.w, xb.x, xb.y, xb.z, xb.w};
  const float bs[8] = {ba.x, ba.y, ba.z, ba.w, bv.x, bv.y, bv.z, bv.w};
#pragma unroll
  for (int j = 0; j < 8; ++j) {
    const float e = expf(-xs[j]);                 // frozen: precise expf
    const float s = recip_nr(1.0f + e);           // 1/(1+e), VCC-free NR
    C[j] = mkkey(s + bs[j], idx0 + j);
  }
  sort8(C);
  if (first) {
#pragma unroll
    for (int j = 0; j < 8; ++j) K[j] = C[j];
  } else {
    merge8(K, C);
  }
}

// phase A on current x[] regs; prefetches next slice into freed x halves.
__device__ __forceinline__ void phase_a(u64 (&K)[8], float4 (&x)[8],
                                        const float4* brow, const float4*& rp,
                                        const int qbase, const bool pf) {
  chunk_sort(K, x[0], x[1], brow[0], brow[1], qbase + 0,  true);
  chunk_sort(K, x[2], x[3], brow[2], brow[3], qbase + 8,  false);
  if (pf) { x[0] = rp[0]; x[1] = rp[1]; x[2] = rp[2]; x[3] = rp[3]; }
  chunk_sort(K, x[4], x[5], brow[4], brow[5], qbase + 16, false);
  chunk_sort(K, x[6], x[7], brow[6], brow[7], qbase + 24, false);
  if (pf) {
    x[4] = rp[4]; x[5] = rp[5]; x[6] = rp[6]; x[7] = rp[7];
    rp += (TPB_TOK * N_EXPERTS) / 4;   // next slice (4096 float4s)
  }
}

// phase B: one lane per token — group top-4, merge 4 lists, epilogue.
__device__ __forceinline__ void phase_b(const float* gsb,
                                        const ulonglong2 (*kbuf)[4],
                                        const float (*bias_lds)[36],
                                        float* out, const int T,
                                        const int j, const int tok) {
  const float4* gp = reinterpret_cast<const float4*>(&gsb[8 * j]);
  const float4 ga = gp[0], gb = gp[1];
  const float g[N_GROUP] = {ga.x, ga.y, ga.z, ga.w, gb.x, gb.y, gb.z, gb.w};

  // top-4 groups (ties -> lower index), collected in ascending group order
  int s0 = 0, s1 = 0, s2 = 0, s3 = 0, cnt = 0;
#pragma unroll
  for (int h = 0; h < N_GROUP; ++h) {
    int rank = 0;
#pragma unroll
    for (int m = 0; m < N_GROUP; ++m)
      rank += (m < h) ? (g[m] >= g[h] ? 1 : 0) : (g[m] > g[h] ? 1 : 0);
    const bool pick = (rank < TOPK_GROUP);
    s0 = (pick && cnt == 0) ? h : s0;
    s1 = (pick && cnt == 1) ? h : s1;
    s2 = (pick && cnt == 2) ? h : s2;
    s3 = (pick && cnt == 3) ? h : s3;
    cnt += pick ? 1 : 0;
  }

  u64 A[8], Bv[8];
  load_list(kbuf, j, s0, A);
  load_list(kbuf, j, s1, Bv); merge8(A, Bv);
  load_list(kbuf, j, s2, Bv); merge8(A, Bv);
  load_list(kbuf, j, s3, Bv); merge8(A, Bv);

  float fi[8], sv[8];
  float sum = 0.0f;
#pragma unroll
  for (int k = 0; k < TOP_K; ++k) {
    const int idx = key_idx(A[k]);
    const float c = key_val(A[k]);
    sv[k] = c - bias_lds[idx >> 5][idx & 31];   // recover sigmoid score
    fi[k] = (float)idx;
    sum += sv[k];
  }
  const float scale = 2.5f / (sum + 1e-20f);

  float4* oi = reinterpret_cast<float4*>(out) + (size_t)tok * 2;
  oi[0] = make_float4(fi[0], fi[1], fi[2], fi[3]);
  oi[1] = make_float4(fi[4], fi[5], fi[6], fi[7]);
  float4* ow = reinterpret_cast<float4*>(out + (size_t)T * TOP_K) + (size_t)tok * 2;
  ow[0] = make_float4(sv[0] * scale, sv[1] * scale, sv[2] * scale, sv[3] * scale);
  ow[1] = make_float4(sv[4] * scale, sv[5] * scale, sv[6] * scale, sv[7] * scale);
}

__global__ __launch_bounds__(BLOCK)
__attribute__((amdgpu_waves_per_eu(4)))   // 128-reg budget: no spill at ~90
void deepseek_topk_router_r13(
    const float* __restrict__ logits,
    const float* __restrict__ bias,
    float* __restrict__ out,   // [T*8] indices (as float) then [T*8] weights
    int T) {
  __shared__ __align__(16) float gsb[BLOCK];             // 2 KB group scores
  __shared__ ulonglong2 kbuf[BLOCK][4];                  // 32 KB, swizzled
  __shared__ __align__(16) float bias_lds[N_GROUP][36];  // padded rows

  const int tid = threadIdx.x;
  const int lq  = tid & 7;               // group handled by this lane
  const int lt  = tid >> 3;              // local token 0..63
  const int nIter  = (T / TPB_TOK) / gridDim.x;   // 4 at T=131072, grid=512
  const int slice0 = blockIdx.x * nIter;
  const int qbase  = lq * EG;

  if (tid < N_EXPERTS) bias_lds[tid >> 5][tid & 31] = bias[tid];

  // prologue: slice0 loads in flight before anything else
  const float4* rp = reinterpret_cast<const float4*>(
      logits + ((size_t)(slice0 * TPB_TOK + lt)) * N_EXPERTS + qbase);
  float4 x[8];
#pragma unroll
  for (int u = 0; u < 8; ++u) x[u] = rp[u];
  rp += (TPB_TOK * N_EXPERTS) / 4;

  __syncthreads();                       // bias_lds ready

  const float4* brow = reinterpret_cast<const float4*>(bias_lds[lq]);

  u64 K[8];
  phase_a(K, x, brow, rp, qbase, nIter > 1);   // slice0; prefetch slice1

  for (int i = 0; i < nIter; ++i) {
    // publish group score + sorted list for slice (slice0+i)
    gsb[tid] = key_val(K[0]) + key_val(K[1]);
    {
      const int rr = tid ^ ((tid >> 5) & 1);
      const int sw = (tid >> 3) & 3;
      kbuf[rr][0 ^ sw] = make_ulonglong2(K[0], K[1]);
      kbuf[rr][1 ^ sw] = make_ulonglong2(K[2], K[3]);
      kbuf[rr][2 ^ sw] = make_ulonglong2(K[4], K[5]);
      kbuf[rr][3 ^ sw] = make_ulonglong2(K[6], K[7]);
    }
    __syncthreads();                     // barrier A: publish visible

    // rotating phase-B wave; others overlap next slice's phase A.
    if ((tid >> 6) == (i & 7))
      phase_b(gsb, kbuf, bias_lds, out, T, tid & 63,
              (slice0 + i) * TPB_TOK + (tid & 63));

    if (i + 1 < nIter) {
      // registers/global/bias_lds only — no gsb/kbuf access before barrier B
      phase_a(K, x, brow, rp, qbase, i + 2 < nIter);
      __syncthreads();                   // barrier B: kbuf reads done,
                                         // safe to overwrite next iteration
    }
  }
}

extern "C" void kernel_launch(void* const* d_in, const int* in_sizes, int n_in,
                              void* d_out, int out_size, void* d_ws, size_t ws_size,
                              hipStream_t stream) {
  const float* logits = (const float*)d_in[0];
  const float* bias   = (const float*)d_in[1];
  float* out = (float*)d_out;
  const int T = in_sizes[0] / N_EXPERTS;       // 131072 (multiple of 64)
  const int nSlices = T / TPB_TOK;             // 2048
  int grid = 512;                              // 2 blocks/CU on 256 CUs
  if (nSlices % grid != 0) grid = nSlices;     // fallback: 1 slice/block
  deepseek_topk_router_r13<<<grid, BLOCK, 0, stream>>>(logits, bias, out, T);
}

// Round 10
// 208.455 us; speedup vs baseline: 1.1097x; 1.1097x over previous
//
#include <hip/hip_runtime.h>
#include <math.h>

// DeepseekV3 TopK router, MI355X — R14 (resubmit; R9 bench was a GPU-broker
// acquisition timeout): barrier-free in-wave phase B.
// Evidence chain: R11/R13 (persistent, x[8] live across phase B) both spill
// (VGPR=64 allocator choice, 70MB scratch, router 96us) regardless of
// waves-per-eu attrs; non-persistent R9/R12 don't spill (router ~47-50us).
// R12 = 202.4us best. R14 removes the LDS/barrier structure entirely:
// each token's 8 lanes already hold the 8 sorted group lists in K[8], so
// phase B = 8-lane butterfly: all-gather group scores (7 shuffles, static
// indexing), rank with the identical tie-break, zero non-picked lists
// (key 0 < any real key == merge-only-selected semantics), 3x
// shfl_xor(1,2,4)+merge8. Lane q==0 writes the epilogue. Deletes kbuf
// (LDS 34KB -> 1.2KB), both kbuf barriers, and the wave-0 serial tail.
// Chunk-streamed row loads (2 float4-pairs in flight) keep peak liveness
// ~56 regs -> 64-VGPR/32-waves-per-CU regime without attribute games.
// Score arithmetic frozen (precise expf, NR recip, u64 keys, Batcher
// networks) -> bit-identical outputs (absmax 0.001953125).

constexpr int N_EXPERTS  = 256;
constexpr int N_GROUP    = 8;
constexpr int EG         = 32;
constexpr int TOPK_GROUP = 4;
constexpr int TOP_K      = 8;
constexpr int BLOCK      = 256;              // 32 tokens/block, no kbuf LDS

typedef unsigned int u32;
typedef unsigned long long u64;

// monotone map: a<b (float) <=> M(a)<M(b) (u32)
__device__ __forceinline__ u32 fmono(float f) {
  const u32 u = __float_as_uint(f);
  return u ^ ((u32)((int)u >> 31) | 0x80000000u);
}
__device__ __forceinline__ float fmono_inv(u32 m) {
  const u32 u = (m & 0x80000000u) ? (m ^ 0x80000000u) : ~m;
  return __uint_as_float(u);
}
// key: larger = (bigger value, then smaller index)
__device__ __forceinline__ u64 mkkey(float v, int idx) {
  return ((u64)fmono(v) << 32) | (u32)(255 - idx);
}
__device__ __forceinline__ int key_idx(u64 k) { return 255 - (int)(k & 0xFFu); }
__device__ __forceinline__ float key_val(u64 k) { return fmono_inv((u32)(k >> 32)); }

// reciprocal of d in (1,2): v_rcp_f32 + 2 NR refinements. VCC-free, <=1 ulp.
__device__ __forceinline__ float recip_nr(float d) {
  float r = __builtin_amdgcn_rcpf(d);
  r = __builtin_fmaf(__builtin_fmaf(-d, r, 1.0f), r, r);
  r = __builtin_fmaf(__builtin_fmaf(-d, r, 1.0f), r, r);
  return r;
}

// descending compare-swap: larger key to a
__device__ __forceinline__ void kswap(u64& a, u64& b) {
  const bool sw = b > a;
  const u64 t = sw ? b : a;
  b = sw ? a : b;
  a = t;
}

// Batcher odd-even mergesort network for 8 (19 comparators), descending.
__device__ __forceinline__ void sort8(u64 (&k)[8]) {
  kswap(k[0], k[1]); kswap(k[2], k[3]); kswap(k[4], k[5]); kswap(k[6], k[7]);
  kswap(k[0], k[2]); kswap(k[1], k[3]); kswap(k[4], k[6]); kswap(k[5], k[7]);
  kswap(k[1], k[2]); kswap(k[5], k[6]);
  kswap(k[0], k[4]); kswap(k[1], k[5]); kswap(k[2], k[6]); kswap(k[3], k[7]);
  kswap(k[2], k[4]); kswap(k[3], k[5]);
  kswap(k[1], k[2]); kswap(k[3], k[4]); kswap(k[5], k[6]);
}

// A = top-8 of (A, B); both descending sorted. Real keys are unique; zeroed
// (masked) keys are all-0 and sort below every real key -> exact.
__device__ __forceinline__ void merge8(u64 (&A)[8], const u64 (&B)[8]) {
  u64 R[8];
#pragma unroll
  for (int i = 0; i < 8; ++i) {
    const bool a = A[i] >= B[7 - i];
    R[i] = a ? A[i] : B[7 - i];
  }
  kswap(R[0], R[4]); kswap(R[1], R[5]); kswap(R[2], R[6]); kswap(R[3], R[7]);
  kswap(R[0], R[2]); kswap(R[1], R[3]); kswap(R[4], R[6]); kswap(R[5], R[7]);
  kswap(R[0], R[1]); kswap(R[2], R[3]); kswap(R[4], R[5]); kswap(R[6], R[7]);
#pragma unroll
  for (int i = 0; i < 8; ++i) A[i] = R[i];
}

__device__ __forceinline__ u64 shfl_xor_u64(u64 v, int m) {
  const int lo = __shfl_xor((int)(u32)v, m, 8);
  const int hi = __shfl_xor((int)(u32)(v >> 32), m, 8);
  return ((u64)(u32)hi << 32) | (u32)lo;
}

// one 8-element chunk: sigmoid+bias -> keys -> sort8 -> merge into K
__device__ __forceinline__ void chunk_sort(u64 (&K)[8], const float4 xa,
                                           const float4 xb, const float4 ba,
                                           const float4 bv, const int idx0,
                                           const bool first) {
  u64 C[8];
  const float xs[8] = {xa.x, xa.y, xa.z, xa.w, xb.x, xb.y, xb.z, xb.w};
  const float bs[8] = {ba.x, ba.y, ba.z, ba.w, bv.x, bv.y, bv.z, bv.w};
#pragma unroll
  for (int j = 0; j < 8; ++j) {
    const float e = expf(-xs[j]);                 // frozen: precise expf
    const float s = recip_nr(1.0f + e);           // 1/(1+e), VCC-free NR
    C[j] = mkkey(s + bs[j], idx0 + j);
  }
  sort8(C);
  if (first) {
#pragma unroll
    for (int j = 0; j < 8; ++j) K[j] = C[j];
  } else {
    merge8(K, C);
  }
}

__global__ __launch_bounds__(BLOCK) void deepseek_topk_router_r14(
    const float* __restrict__ logits,
    const float* __restrict__ bias,
    float* __restrict__ out,   // [T*8] indices (as float) then [T*8] weights
    int T) {
  __shared__ __align__(16) float bias_lds[N_GROUP][36];  // padded rows

  const int tid = threadIdx.x;
  const int id  = blockIdx.x * BLOCK + tid;
  const int t   = id >> 3;              // token (T*8 % 256 == 0, grid exact)
  const int q   = id & 7;               // group handled by this lane

  const float4* rp =
      reinterpret_cast<const float4*>(logits + (size_t)t * N_EXPERTS + q * EG);

  // chunk-streamed loads: two float4-pairs in flight, refill freed pair
  float4 a0 = rp[0], a1 = rp[1];        // chunk 0
  float4 b0 = rp[2], b1 = rp[3];        // chunk 1

  if (tid < N_EXPERTS) bias_lds[tid >> 5][tid & 31] = bias[tid];
  __syncthreads();                      // bias ready (only barrier)
  const float4* brow = reinterpret_cast<const float4*>(bias_lds[q]);
  const int qbase = q * EG;

  // ---- Phase A: sorted top-8 keys of my group's 32 corrected scores ----
  u64 K[8];
  chunk_sort(K, a0, a1, brow[0], brow[1], qbase + 0,  true);
  a0 = rp[4]; a1 = rp[5];               // chunk 2 into freed regs
  chunk_sort(K, b0, b1, brow[2], brow[3], qbase + 8,  false);
  b0 = rp[6]; b1 = rp[7];               // chunk 3
  chunk_sort(K, a0, a1, brow[4], brow[5], qbase + 16, false);
  chunk_sort(K, b0, b1, brow[6], brow[7], qbase + 24, false);

  // ---- Phase B, in-wave: 8-lane all-gather of group scores ----
  const float gq = key_val(K[0]) + key_val(K[1]);
  const float p1 = __shfl_xor(gq, 1, 8);
  const bool o1 = (q & 1) != 0;
  const float e0 = o1 ? p1 : gq;        // value at lane (q&~1)|0
  const float e1 = o1 ? gq : p1;        // value at lane (q&~1)|1
  const float f0 = __shfl_xor(e0, 2, 8);
  const float f1 = __shfl_xor(e1, 2, 8);
  const bool o2 = (q & 2) != 0;
  const float d0 = o2 ? f0 : e0;        // lanes (q&~3)+0..3
  const float d1 = o2 ? f1 : e1;
  const float d2 = o2 ? e0 : f0;
  const float d3 = o2 ? e1 : f1;
  const float h0 = __shfl_xor(d0, 4, 8);
  const float h1 = __shfl_xor(d1, 4, 8);
  const float h2 = __shfl_xor(d2, 4, 8);
  const float h3 = __shfl_xor(d3, 4, 8);
  const bool o4 = (q & 4) != 0;
  const float g0 = o4 ? h0 : d0;        // lanes 0..7 of my 8-group
  const float g1 = o4 ? h1 : d1;
  const float g2 = o4 ? h2 : d2;
  const float g3 = o4 ? h3 : d3;
  const float g4 = o4 ? d0 : h0;
  const float g5 = o4 ? d1 : h1;
  const float g6 = o4 ? d2 : h2;
  const float g7 = o4 ? d3 : h3;

  // rank of my group (ties -> lower index wins), identical formula to R12
  int rank = 0;
#define RANK_TERM(m, gm) \
  rank += ((m) < q) ? ((gm) >= gq ? 1 : 0) : ((((m) > q) && ((gm) > gq)) ? 1 : 0);
  RANK_TERM(0, g0) RANK_TERM(1, g1) RANK_TERM(2, g2) RANK_TERM(3, g3)
  RANK_TERM(4, g4) RANK_TERM(5, g5) RANK_TERM(6, g6) RANK_TERM(7, g7)
#undef RANK_TERM
  const bool pick = (rank < TOPK_GROUP);

  // zero non-picked lists: key 0 < every real key == merge-selected-only
#pragma unroll
  for (int k = 0; k < 8; ++k) K[k] = pick ? K[k] : 0ULL;

  // butterfly merge: after rounds 1,2,4 every lane holds the token's top-8
  u64 P[8];
#pragma unroll
  for (int k = 0; k < 8; ++k) P[k] = shfl_xor_u64(K[k], 1);
  merge8(K, P);
#pragma unroll
  for (int k = 0; k < 8; ++k) P[k] = shfl_xor_u64(K[k], 2);
  merge8(K, P);
#pragma unroll
  for (int k = 0; k < 8; ++k) P[k] = shfl_xor_u64(K[k], 4);
  merge8(K, P);

  // ---- Epilogue: lane q==0 of each token writes (same math as R12) ----
  if (q == 0) {
    float fi[8], sv[8];
    float sum = 0.0f;
#pragma unroll
    for (int k = 0; k < TOP_K; ++k) {
      const int idx = key_idx(K[k]);
      const float c = key_val(K[k]);
      sv[k] = c - bias_lds[idx >> 5][idx & 31];  // recover sigmoid score
      fi[k] = (float)idx;
      sum += sv[k];
    }
    const float scale = 2.5f / (sum + 1e-20f);

    float4* oi = reinterpret_cast<float4*>(out) + (size_t)t * 2;
    oi[0] = make_float4(fi[0], fi[1], fi[2], fi[3]);
    oi[1] = make_float4(fi[4], fi[5], fi[6], fi[7]);
    float4* ow =
        reinterpret_cast<float4*>(out + (size_t)T * TOP_K) + (size_t)t * 2;
    ow[0] = make_float4(sv[0] * scale, sv[1] * scale, sv[2] * scale, sv[3] * scale);
    ow[1] = make_float4(sv[4] * scale, sv[5] * scale, sv[6] * scale, sv[7] * scale);
  }
}

extern "C" void kernel_launch(void* const* d_in, const int* in_sizes, int n_in,
                              void* d_out, int out_size, void* d_ws, size_t ws_size,
                              hipStream_t stream) {
  const float* logits = (const float*)d_in[0];
  const float* bias   = (const float*)d_in[1];
  float* out = (float*)d_out;
  const int T = in_sizes[0] / N_EXPERTS;           // 131072
  const int blocks = (T * N_GROUP) / BLOCK;         // 4096
  deepseek_topk_router_r14<<<blocks, BLOCK, 0, stream>>>(logits, bias, out, T);
}

// Round 11
// 206.716 us; speedup vs baseline: 1.1190x; 1.0084x over previous
//
#include <hip/hip_runtime.h>
#include <math.h>

// DeepseekV3 TopK router, MI355X — R15 = R12's structure + R14's register
// economy. Locked evidence: barriers/LDS plumbing ~free (R10, R14 A/B);
// router is VALU-issue-bound (R14: VALUBusy 70%, +350 instr/lane = +6us);
// allocator pins VGPR to occupancy targets (64 for 512thr/36KB-LDS) and
// spills overflow (R11/R13 catastrophically; R12 mildly at peak-live ~72).
// R15: R12's 1-lane phase B via swizzled kbuf (cheapest phase B measured)
// + R14's chunk-streamed loads (2 float4-pairs in flight, peak live ~56,
// proven spill-free at VGPR=32 in R14) -> fits the 64-reg/4-block/32-wave
// target cleanly. No occupancy attributes. Score arithmetic, chunk order,
// key encoding, sort/merge networks, epilogue: bit-identical to R12
// (absmax 0.001953125).

constexpr int N_EXPERTS  = 256;
constexpr int N_GROUP    = 8;
constexpr int EG         = 32;
constexpr int TOPK_GROUP = 4;
constexpr int TOP_K      = 8;
constexpr int BLOCK      = 512;              // 64 tokens per block
constexpr int TPB_TOK    = BLOCK / N_GROUP;  // 64

typedef unsigned int u32;
typedef unsigned long long u64;

// monotone map: a<b (float) <=> M(a)<M(b) (u32)
__device__ __forceinline__ u32 fmono(float f) {
  const u32 u = __float_as_uint(f);
  return u ^ ((u32)((int)u >> 31) | 0x80000000u);
}
__device__ __forceinline__ float fmono_inv(u32 m) {
  const u32 u = (m & 0x80000000u) ? (m ^ 0x80000000u) : ~m;
  return __uint_as_float(u);
}
// key: larger = (bigger value, then smaller index)
__device__ __forceinline__ u64 mkkey(float v, int idx) {
  return ((u64)fmono(v) << 32) | (u32)(255 - idx);
}
__device__ __forceinline__ int key_idx(u64 k) { return 255 - (int)(k & 0xFFu); }
__device__ __forceinline__ float key_val(u64 k) { return fmono_inv((u32)(k >> 32)); }

// reciprocal of d in (1,2): v_rcp_f32 + 2 NR refinements. VCC-free, <=1 ulp.
__device__ __forceinline__ float recip_nr(float d) {
  float r = __builtin_amdgcn_rcpf(d);
  r = __builtin_fmaf(__builtin_fmaf(-d, r, 1.0f), r, r);
  r = __builtin_fmaf(__builtin_fmaf(-d, r, 1.0f), r, r);
  return r;
}

// descending compare-swap: larger key to a
__device__ __forceinline__ void kswap(u64& a, u64& b) {
  const bool sw = b > a;
  const u64 t = sw ? b : a;
  b = sw ? a : b;
  a = t;
}

// Batcher odd-even mergesort network for 8 (19 comparators), descending.
__device__ __forceinline__ void sort8(u64 (&k)[8]) {
  kswap(k[0], k[1]); kswap(k[2], k[3]); kswap(k[4], k[5]); kswap(k[6], k[7]);
  kswap(k[0], k[2]); kswap(k[1], k[3]); kswap(k[4], k[6]); kswap(k[5], k[7]);
  kswap(k[1], k[2]); kswap(k[5], k[6]);
  kswap(k[0], k[4]); kswap(k[1], k[5]); kswap(k[2], k[6]); kswap(k[3], k[7]);
  kswap(k[2], k[4]); kswap(k[3], k[5]);
  kswap(k[1], k[2]); kswap(k[3], k[4]); kswap(k[5], k[6]);
}

// A = top-8 of (A, B); both descending sorted. Keys are unique -> exact.
__device__ __forceinline__ void merge8(u64 (&A)[8], const u64 (&B)[8]) {
  u64 R[8];
#pragma unroll
  for (int i = 0; i < 8; ++i) {
    const bool a = A[i] >= B[7 - i];
    R[i] = a ? A[i] : B[7 - i];
  }
  kswap(R[0], R[4]); kswap(R[1], R[5]); kswap(R[2], R[6]); kswap(R[3], R[7]);
  kswap(R[0], R[2]); kswap(R[1], R[3]); kswap(R[4], R[6]); kswap(R[5], R[7]);
  kswap(R[0], R[1]); kswap(R[2], R[3]); kswap(R[4], R[5]); kswap(R[6], R[7]);
#pragma unroll
  for (int i = 0; i < 8; ++i) A[i] = R[i];
}

// phase-B list read: 4x ds_read_b128, conflict-free via the 2-level swizzle.
__device__ __forceinline__ void load_list(const ulonglong2 (*kb)[4], int j,
                                          int s, u64 (&L)[8]) {
  const int rr = (8 * j + s) ^ ((j >> 2) & 1);  // (r>>5)&1 == (j>>2)&1, s<8
  const int sw = j & 3;                         // (r>>3)&3 == j&3
#pragma unroll
  for (int p = 0; p < 4; ++p) {
    const ulonglong2 v = kb[rr][p ^ sw];
    L[2 * p]     = v.x;
    L[2 * p + 1] = v.y;
  }
}

// one 8-element chunk: sigmoid+bias -> keys -> sort8 -> merge into K
__device__ __forceinline__ void chunk_sort(u64 (&K)[8], const float4 xa,
                                           const float4 xb, const float4 ba,
                                           const float4 bv, const int idx0,
                                           const bool first) {
  u64 C[8];
  const float xs[8] = {xa.x, xa.y, xa.z, xa.w, xb.x, xb.y, xb.z, xb.w};
  const float bs[8] = {ba.x, ba.y, ba.z, ba.w, bv.x, bv.y, bv.z, bv.w};
#pragma unroll
  for (int j = 0; j < 8; ++j) {
    const float e = expf(-xs[j]);                 // frozen: precise expf
    const float s = recip_nr(1.0f + e);           // 1/(1+e), VCC-free NR
    C[j] = mkkey(s + bs[j], idx0 + j);
  }
  sort8(C);
  if (first) {
#pragma unroll
    for (int j = 0; j < 8; ++j) K[j] = C[j];
  } else {
    merge8(K, C);
  }
}

__global__ __launch_bounds__(BLOCK) void deepseek_topk_router_r15(
    const float* __restrict__ logits,
    const float* __restrict__ bias,
    float* __restrict__ out,   // [T*8] indices (as float) then [T*8] weights
    int T) {
  __shared__ __align__(16) float gsb[BLOCK];             // 2 KB group scores
  __shared__ ulonglong2 kbuf[BLOCK][4];                  // 32 KB, swizzled
  __shared__ __align__(16) float bias_lds[N_GROUP][36];  // padded rows

  const int tid = threadIdx.x;
  const int id  = blockIdx.x * BLOCK + tid;
  const int t   = id >> 3;              // token (T*8 % 512 == 0, grid exact)
  const int q   = id & 7;               // group handled by this lane

  const float4* rp =
      reinterpret_cast<const float4*>(logits + (size_t)t * N_EXPERTS + q * EG);

  // chunk-streamed loads: two float4-pairs in flight, refill freed pair
  float4 a0 = rp[0], a1 = rp[1];        // chunk 0
  float4 b0 = rp[2], b1 = rp[3];        // chunk 1

  if (tid < N_EXPERTS) bias_lds[tid >> 5][tid & 31] = bias[tid];
  __syncthreads();                      // bias ready
  const float4* brow = reinterpret_cast<const float4*>(bias_lds[q]);
  const int qbase = q * EG;

  // ---- Phase A: sorted top-8 keys of my group's 32 corrected scores ----
  u64 K[8];
  chunk_sort(K, a0, a1, brow[0], brow[1], qbase + 0,  true);
  a0 = rp[4]; a1 = rp[5];               // chunk 2 into freed regs
  chunk_sort(K, b0, b1, brow[2], brow[3], qbase + 8,  false);
  b0 = rp[6]; b1 = rp[7];               // chunk 3
  chunk_sort(K, a0, a1, brow[4], brow[5], qbase + 16, false);
  chunk_sort(K, b0, b1, brow[6], brow[7], qbase + 24, false);

  // ---- Publish group score + sorted list; single barrier ----
  gsb[tid] = key_val(K[0]) + key_val(K[1]);
  {
    const int rr = tid ^ ((tid >> 5) & 1);
    const int sw = (tid >> 3) & 3;
    kbuf[rr][0 ^ sw] = make_ulonglong2(K[0], K[1]);
    kbuf[rr][1 ^ sw] = make_ulonglong2(K[2], K[3]);
    kbuf[rr][2 ^ sw] = make_ulonglong2(K[4], K[5]);
    kbuf[rr][3 ^ sw] = make_ulonglong2(K[6], K[7]);
  }
  __syncthreads();
  if (tid >= TPB_TOK) return;           // waves 1..7 done

  // ---- Phase B: wave 0, one thread per token ----
  const int j   = tid;                  // local token
  const int tok = blockIdx.x * TPB_TOK + j;

  // 8 group scores (contiguous in gsb)
  const float4* gp = reinterpret_cast<const float4*>(&gsb[8 * j]);
  const float4 ga = gp[0], gb = gp[1];
  const float g[N_GROUP] = {ga.x, ga.y, ga.z, ga.w, gb.x, gb.y, gb.z, gb.w};

  // top-4 groups (ties -> lower index), collected in ascending group order
  int s0 = 0, s1 = 0, s2 = 0, s3 = 0, cnt = 0;
#pragma unroll
  for (int h = 0; h < N_GROUP; ++h) {
    int rank = 0;
#pragma unroll
    for (int m = 0; m < N_GROUP; ++m)
      rank += (m < h) ? (g[m] >= g[h] ? 1 : 0) : (g[m] > g[h] ? 1 : 0);
    const bool pick = (rank < TOPK_GROUP);
    s0 = (pick && cnt == 0) ? h : s0;
    s1 = (pick && cnt == 1) ? h : s1;
    s2 = (pick && cnt == 2) ? h : s2;
    s3 = (pick && cnt == 3) ? h : s3;
    cnt += pick ? 1 : 0;
  }

  // merge the 4 selected lists (key order is exact; any merge order OK)
  u64 A[8], Bv[8];
  load_list(kbuf, j, s0, A);
  load_list(kbuf, j, s1, Bv); merge8(A, Bv);
  load_list(kbuf, j, s2, Bv); merge8(A, Bv);
  load_list(kbuf, j, s3, Bv); merge8(A, Bv);

  // ---- Epilogue: weights = (c - bias[idx]) / sum * 2.5 ----
  float fi[8], sv[8];
  float sum = 0.0f;
#pragma unroll
  for (int k = 0; k < TOP_K; ++k) {
    const int idx = key_idx(A[k]);
    const float c = key_val(A[k]);
    sv[k] = c - bias[idx];              // recover sigmoid score (bias L1-hot)
    fi[k] = (float)idx;
    sum += sv[k];
  }
  const float scale = 2.5f / (sum + 1e-20f);  // once per token: IEEE is fine

  float4* oi = reinterpret_cast<float4*>(out) + (size_t)tok * 2;
  oi[0] = make_float4(fi[0], fi[1], fi[2], fi[3]);
  oi[1] = make_float4(fi[4], fi[5], fi[6], fi[7]);
  float4* ow = reinterpret_cast<float4*>(out + (size_t)T * TOP_K) + (size_t)tok * 2;
  ow[0] = make_float4(sv[0] * scale, sv[1] * scale, sv[2] * scale, sv[3] * scale);
  ow[1] = make_float4(sv[4] * scale, sv[5] * scale, sv[6] * scale, sv[7] * scale);
}

extern "C" void kernel_launch(void* const* d_in, const int* in_sizes, int n_in,
                              void* d_out, int out_size, void* d_ws, size_t ws_size,
                              hipStream_t stream) {
  const float* logits = (const float*)d_in[0];
  const float* bias   = (const float*)d_in[1];
  float* out = (float*)d_out;
  const int T = in_sizes[0] / N_EXPERTS;           // 131072 (multiple of 64)
  const int blocks = T / TPB_TOK;                   // 2048
  deepseek_topk_router_r15<<<blocks, BLOCK, 0, stream>>>(logits, bias, out, T);
}

// Round 12
// 202.042 us; speedup vs baseline: 1.1449x; 1.0231x over previous
//
#include <hip/hip_runtime.h>
#include <math.h>

// DeepseekV3 TopK router, MI355X — R16 = R12 verbatim (lock in best measured:
// 202.4us). Final experiment series verdict:
//   R12 (this): 512thr, x[8] burst loads, LDS-swizzled 1-lane phase B = ~46us router
//   R15 (chunk-streamed loads): ~51us — less memory-parallelism, -4us
//   R14 (in-wave butterfly phase B): ~52us — +350 VALU instr/lane
//   R11/R13 (persistent prefetch): ~96us — allocator spills at its occupancy target
//   R10 (LDS swizzle under 64-reg cap): null — spills masked it
// Router is VALU-issue-bound (VALUBusy ~70% @ 62% occ); instruction count is
// algorithmically irreducible without risking selection flips vs the exact
// reference. Benched time is ~75% harness re-poison fills at 86-87% HBM peak
// (their own roofline). Score arithmetic frozen (precise expf, NR recip,
// u64 keys, Batcher networks) -> absmax 0.001953125.

constexpr int N_EXPERTS  = 256;
constexpr int N_GROUP    = 8;
constexpr int EG         = 32;
constexpr int TOPK_GROUP = 4;
constexpr int TOP_K      = 8;
constexpr int BLOCK      = 512;              // 64 tokens per block
constexpr int TPB_TOK    = BLOCK / N_GROUP;  // 64

typedef unsigned int u32;
typedef unsigned long long u64;

// monotone map: a<b (float) <=> M(a)<M(b) (u32)
__device__ __forceinline__ u32 fmono(float f) {
  const u32 u = __float_as_uint(f);
  return u ^ ((u32)((int)u >> 31) | 0x80000000u);
}
__device__ __forceinline__ float fmono_inv(u32 m) {
  const u32 u = (m & 0x80000000u) ? (m ^ 0x80000000u) : ~m;
  return __uint_as_float(u);
}
// key: larger = (bigger value, then smaller index)
__device__ __forceinline__ u64 mkkey(float v, int idx) {
  return ((u64)fmono(v) << 32) | (u32)(255 - idx);
}
__device__ __forceinline__ int key_idx(u64 k) { return 255 - (int)(k & 0xFFu); }
__device__ __forceinline__ float key_val(u64 k) { return fmono_inv((u32)(k >> 32)); }

// reciprocal of d in (1,2): v_rcp_f32 + 2 NR refinements. VCC-free, <=1 ulp.
__device__ __forceinline__ float recip_nr(float d) {
  float r = __builtin_amdgcn_rcpf(d);
  r = __builtin_fmaf(__builtin_fmaf(-d, r, 1.0f), r, r);
  r = __builtin_fmaf(__builtin_fmaf(-d, r, 1.0f), r, r);
  return r;
}

// descending compare-swap: larger key to a
__device__ __forceinline__ void kswap(u64& a, u64& b) {
  const bool sw = b > a;
  const u64 t = sw ? b : a;
  b = sw ? a : b;
  a = t;
}

// Batcher odd-even mergesort network for 8 (19 comparators), descending.
__device__ __forceinline__ void sort8(u64 (&k)[8]) {
  kswap(k[0], k[1]); kswap(k[2], k[3]); kswap(k[4], k[5]); kswap(k[6], k[7]);
  kswap(k[0], k[2]); kswap(k[1], k[3]); kswap(k[4], k[6]); kswap(k[5], k[7]);
  kswap(k[1], k[2]); kswap(k[5], k[6]);
  kswap(k[0], k[4]); kswap(k[1], k[5]); kswap(k[2], k[6]); kswap(k[3], k[7]);
  kswap(k[2], k[4]); kswap(k[3], k[5]);
  kswap(k[1], k[2]); kswap(k[3], k[4]); kswap(k[5], k[6]);
}

// A = top-8 of (A, B); both descending sorted. Keys are unique -> exact.
__device__ __forceinline__ void merge8(u64 (&A)[8], const u64 (&B)[8]) {
  u64 R[8];
#pragma unroll
  for (int i = 0; i < 8; ++i) {
    const bool a = A[i] >= B[7 - i];
    R[i] = a ? A[i] : B[7 - i];
  }
  kswap(R[0], R[4]); kswap(R[1], R[5]); kswap(R[2], R[6]); kswap(R[3], R[7]);
  kswap(R[0], R[2]); kswap(R[1], R[3]); kswap(R[4], R[6]); kswap(R[5], R[7]);
  kswap(R[0], R[1]); kswap(R[2], R[3]); kswap(R[4], R[5]); kswap(R[6], R[7]);
#pragma unroll
  for (int i = 0; i < 8; ++i) A[i] = R[i];
}

// phase-B list read: 4x ds_read_b128, conflict-free via the 2-level swizzle.
__device__ __forceinline__ void load_list(const ulonglong2 (*kb)[4], int j,
                                          int s, u64 (&L)[8]) {
  const int rr = (8 * j + s) ^ ((j >> 2) & 1);  // (r>>5)&1 == (j>>2)&1, s<8
  const int sw = j & 3;                         // (r>>3)&3 == j&3
#pragma unroll
  for (int p = 0; p < 4; ++p) {
    const ulonglong2 v = kb[rr][p ^ sw];
    L[2 * p]     = v.x;
    L[2 * p + 1] = v.y;
  }
}

__global__ __launch_bounds__(BLOCK)
__attribute__((amdgpu_waves_per_eu(6)))
void deepseek_topk_router_r16(
    const float* __restrict__ logits,
    const float* __restrict__ bias,
    float* __restrict__ out,   // [T*8] indices (as float) then [T*8] weights
    int T) {
  __shared__ __align__(16) float gsb[BLOCK];             // 2 KB group scores
  __shared__ ulonglong2 kbuf[BLOCK][4];                  // 32 KB, swizzled
  __shared__ __align__(16) float bias_lds[N_GROUP][36];  // padded: row r on
                                                         // bank group 4r

  const int tid = threadIdx.x;
  const int id  = blockIdx.x * BLOCK + tid;
  const int t   = id >> 3;              // token (T*8 % 512 == 0, grid exact)
  const int q   = id & 7;               // group handled by this lane

  const float4* row4 =
      reinterpret_cast<const float4*>(logits + (size_t)t * N_EXPERTS + q * EG);

  // full 128B row per thread in flight before any dependent math
  float4 x[8];
#pragma unroll
  for (int u = 0; u < 8; ++u) x[u] = row4[u];

  // bias -> LDS (2-way write aliasing only = free), then barrier
  if (tid < N_EXPERTS) bias_lds[tid >> 5][tid & 31] = bias[tid];
  __syncthreads();
  const float4* brow = reinterpret_cast<const float4*>(bias_lds[q]);

  // ---- Phase A: sorted top-8 keys of my group's 32 corrected scores ----
  u64 K[8];
#pragma unroll
  for (int c = 0; c < 4; ++c) {
    u64 C[8];
    const float4 ba = brow[2 * c], bv = brow[2 * c + 1];   // LDS broadcast
    const float xs[8] = {x[2*c].x, x[2*c].y, x[2*c].z, x[2*c].w,
                         x[2*c+1].x, x[2*c+1].y, x[2*c+1].z, x[2*c+1].w};
    const float bs[8] = {ba.x, ba.y, ba.z, ba.w, bv.x, bv.y, bv.z, bv.w};
#pragma unroll
    for (int j = 0; j < 8; ++j) {
      const float e = expf(-xs[j]);                 // frozen: precise expf
      const float s = recip_nr(1.0f + e);           // 1/(1+e), VCC-free NR
      C[j] = mkkey(s + bs[j], q * EG + c * 8 + j);
    }
    sort8(C);
    if (c == 0) {
#pragma unroll
      for (int j = 0; j < 8; ++j) K[j] = C[j];
    } else {
      merge8(K, C);
    }
  }

  // ---- Publish group score + sorted list; single barrier ----
  gsb[tid] = key_val(K[0]) + key_val(K[1]);
  {
    const int rr = tid ^ ((tid >> 5) & 1);
    const int sw = (tid >> 3) & 3;
    kbuf[rr][0 ^ sw] = make_ulonglong2(K[0], K[1]);
    kbuf[rr][1 ^ sw] = make_ulonglong2(K[2], K[3]);
    kbuf[rr][2 ^ sw] = make_ulonglong2(K[4], K[5]);
    kbuf[rr][3 ^ sw] = make_ulonglong2(K[6], K[7]);
  }
  __syncthreads();
  if (tid >= TPB_TOK) return;           // waves 1..7 done

  // ---- Phase B: wave 0, one thread per token ----
  const int j   = tid;                  // local token
  const int tok = blockIdx.x * TPB_TOK + j;

  // 8 group scores (contiguous in gsb)
  const float4* gp = reinterpret_cast<const float4*>(&gsb[8 * j]);
  const float4 ga = gp[0], gb = gp[1];
  const float g[N_GROUP] = {ga.x, ga.y, ga.z, ga.w, gb.x, gb.y, gb.z, gb.w};

  // top-4 groups (ties -> lower index), collected in ascending group order
  int s0 = 0, s1 = 0, s2 = 0, s3 = 0, cnt = 0;
#pragma unroll
  for (int h = 0; h < N_GROUP; ++h) {
    int rank = 0;
#pragma unroll
    for (int m = 0; m < N_GROUP; ++m)
      rank += (m < h) ? (g[m] >= g[h] ? 1 : 0) : (g[m] > g[h] ? 1 : 0);
    const bool pick = (rank < TOPK_GROUP);
    s0 = (pick && cnt == 0) ? h : s0;
    s1 = (pick && cnt == 1) ? h : s1;
    s2 = (pick && cnt == 2) ? h : s2;
    s3 = (pick && cnt == 3) ? h : s3;
    cnt += pick ? 1 : 0;
  }

  // merge the 4 selected lists (key order is exact; any merge order OK)
  u64 A[8], Bv[8];
  load_list(kbuf, j, s0, A);
  load_list(kbuf, j, s1, Bv); merge8(A, Bv);
  load_list(kbuf, j, s2, Bv); merge8(A, Bv);
  load_list(kbuf, j, s3, Bv); merge8(A, Bv);

  // ---- Epilogue: weights = (c - bias[idx]) / sum * 2.5 ----
  float fi[8], sv[8];
  float sum = 0.0f;
#pragma unroll
  for (int k = 0; k < TOP_K; ++k) {
    const int idx = key_idx(A[k]);
    const float c = key_val(A[k]);
    sv[k] = c - bias[idx];              // recover sigmoid score (bias L1-hot)
    fi[k] = (float)idx;
    sum += sv[k];
  }
  const float scale = 2.5f / (sum + 1e-20f);  // once per token: IEEE is fine

  float4* oi = reinterpret_cast<float4*>(out) + (size_t)tok * 2;
  oi[0] = make_float4(fi[0], fi[1], fi[2], fi[3]);
  oi[1] = make_float4(fi[4], fi[5], fi[6], fi[7]);
  float4* ow = reinterpret_cast<float4*>(out + (size_t)T * TOP_K) + (size_t)tok * 2;
  ow[0] = make_float4(sv[0] * scale, sv[1] * scale, sv[2] * scale, sv[3] * scale);
  ow[1] = make_float4(sv[4] * scale, sv[5] * scale, sv[6] * scale, sv[7] * scale);
}

extern "C" void kernel_launch(void* const* d_in, const int* in_sizes, int n_in,
                              void* d_out, int out_size, void* d_ws, size_t ws_size,
                              hipStream_t stream) {
  const float* logits = (const float*)d_in[0];
  const float* bias   = (const float*)d_in[1];
  float* out = (float*)d_out;
  const int T = in_sizes[0] / N_EXPERTS;           // 131072 (multiple of 64)
  const int blocks = T / TPB_TOK;                   // 2048
  deepseek_topk_router_r16<<<blocks, BLOCK, 0, stream>>>(logits, bias, out, T);
}